// Round 7
// baseline (376.075 us; speedup 1.0000x reference)
//
#include <hip/hip_runtime.h>
#include <hip/hip_bf16.h>

// GNNEncoder: 3-layer GraphSAGE (mean agg), N=50000, E=800000.
// h' = act( mean_agg(x@Wl) + x@(Wr+Ws) + (bl+bs) )   (matmul-first by linearity)
// R7: dispatch-count attack (12 -> 9): memset folded into wpack; p2+scan_b+p4
//     merged into one decoupled-lookback kernel (196 co-resident blocks,
//     device-scope packed flag|value statuses). GEMM/agg unchanged.

#define LB __launch_bounds__

typedef __attribute__((ext_vector_type(8))) short short8;
typedef __attribute__((ext_vector_type(4))) float f32x4;

__device__ __forceinline__ unsigned short bf16_rne(float f) {
  unsigned u = __builtin_bit_cast(unsigned, f);
  unsigned r = u + 0x7fffu + ((u >> 16) & 1u);
  return (unsigned short)(r >> 16);
}
__device__ __forceinline__ float bf16_to_f(unsigned short us) {
  return __builtin_bit_cast(float, (unsigned)us << 16);
}
__device__ __forceinline__ float bits_to_f(unsigned u) {
  return __builtin_bit_cast(float, u);
}

// ---------------- CSR build: bucketed 2-pass sort ----------------
#define BCAP 8192
#define P1_CHUNK 4096
#define FLAG_INC 0x80000000u
#define FLAG_AGG 0x40000000u
#define VAL_MASK 0x3FFFFFFFu

__global__ LB(256) void p1_bucket(const int* __restrict__ src, const int* __restrict__ dst,
                                  int* __restrict__ bcnt, int2* __restrict__ pairs, int E) {
  __shared__ int cnt[256];
  __shared__ int base[256];
  const int tid = threadIdx.x;
  cnt[tid] = 0;
  __syncthreads();
  const int e0 = blockIdx.x * P1_CHUNK;
  int myb[16], myr[16], mys[16], myd[16];
#pragma unroll
  for (int i = 0; i < 16; ++i) {
    int e = e0 + i * 256 + tid;
    myb[i] = -1;
    if (e < E) {
      int s = src[e], d = dst[e];
      int b = d >> 8;
      myb[i] = b;
      mys[i] = s;
      myd[i] = d;
      myr[i] = atomicAdd(&cnt[b], 1);
    }
  }
  __syncthreads();
  base[tid] = (cnt[tid] > 0) ? atomicAdd(&bcnt[tid], cnt[tid]) : 0;
  __syncthreads();
#pragma unroll
  for (int i = 0; i < 16; ++i) {
    int b = myb[i];
    if (b >= 0) {
      int p = base[b] + myr[i];
      if (p < BCAP) pairs[(size_t)b * BCAP + p] = make_int2(mys[i], myd[i]);
    }
  }
}

// Fused: per-bucket hist + local scan + decoupled-lookback global prefix +
// edge placement + row_ptr/scale finalize. One kernel replaces p2+scan_b+p4.
// Safe: 196 blocks, tiny LDS/VGPR -> all co-resident; lookback cannot deadlock.
__global__ LB(256) void p234_kernel(const int2* __restrict__ pairs, const int* __restrict__ bcnt,
                                    unsigned* __restrict__ status, int* __restrict__ row_ptr,
                                    float* __restrict__ scale, int* __restrict__ srcs, int N,
                                    int NB) {
  __shared__ int h[256];
  __shared__ int sc[256];
  __shared__ int cur[256];
  __shared__ int shared_bb;
  const int tid = threadIdx.x;
  const int b = blockIdx.x;
  h[tid] = 0;
  __syncthreads();
  int m = bcnt[b];
  if (m > BCAP) m = BCAP;
  for (int i = tid; i < m; i += 256) {
    atomicAdd(&h[pairs[(size_t)b * BCAP + i].y & 255], 1);
  }
  __syncthreads();
  const int deg = h[tid];
  sc[tid] = deg;
  __syncthreads();
  for (int off = 1; off < 256; off <<= 1) {
    int add = (tid >= off) ? sc[tid - off] : 0;
    __syncthreads();
    sc[tid] += add;
    __syncthreads();
  }
  const int total = sc[255];
  if (tid == 0) {
    __hip_atomic_store(&status[b], FLAG_AGG | (unsigned)total, __ATOMIC_RELEASE,
                       __HIP_MEMORY_SCOPE_AGENT);
    unsigned ex = 0;
    for (int j = b - 1; j >= 0;) {
      unsigned s;
      do {
        s = __hip_atomic_load(&status[j], __ATOMIC_ACQUIRE, __HIP_MEMORY_SCOPE_AGENT);
      } while (s == 0u);
      if (s & FLAG_INC) {
        ex += s & VAL_MASK;
        break;
      }
      ex += s & VAL_MASK;
      --j;
    }
    __hip_atomic_store(&status[b], FLAG_INC | ((unsigned)total + ex), __ATOMIC_RELEASE,
                       __HIP_MEMORY_SCOPE_AGENT);
    shared_bb = (int)ex;
    if (b == NB - 1) row_ptr[N] = (int)(ex + (unsigned)total);
  }
  __syncthreads();
  const int bb = shared_bb;
  const int abs_off = bb + sc[tid] - deg;
  const int node = b * 256 + tid;
  if (node < N) {
    row_ptr[node] = abs_off;
    scale[node] = 1.0f / (float)(deg > 1 ? deg : 1);
  }
  cur[tid] = abs_off;
  __syncthreads();
  for (int i = tid; i < m; i += 256) {
    int2 pr = pairs[(size_t)b * BCAP + i];
    int p = atomicAdd(&cur[pr.y & 255], 1);
    srcs[p] = pr.x;
  }
}

// ---------------- weights -> fragment-ordered hi/lo bf16 + bias; also zeroes bcnt/status ----
__global__ LB(256) void wpack_all(const float* __restrict__ Wl0, const float* __restrict__ Wr0,
                                  const float* __restrict__ Ws0, const float* __restrict__ bl0,
                                  const float* __restrict__ bs0, const float* __restrict__ Wl1,
                                  const float* __restrict__ Wr1, const float* __restrict__ Ws1,
                                  const float* __restrict__ bl1, const float* __restrict__ bs1,
                                  const float* __restrict__ Wl2, const float* __restrict__ Wr2,
                                  const float* __restrict__ Ws2, const float* __restrict__ bl2,
                                  const float* __restrict__ bs2, ushort* __restrict__ Bh0,
                                  ushort* __restrict__ Bo0, float* __restrict__ bb0,
                                  ushort* __restrict__ Bh1, ushort* __restrict__ Bo1,
                                  float* __restrict__ bb1, ushort* __restrict__ Bh2,
                                  ushort* __restrict__ Bo2, float* __restrict__ bb2,
                                  int* __restrict__ bcnt, unsigned* __restrict__ status, int NB) {
  const int layer = blockIdx.y;
  if (layer == 0 && blockIdx.x == 0) {
    for (int i = threadIdx.x; i < NB; i += 256) {
      bcnt[i] = 0;
      status[i] = 0u;
    }
  }
  const float *Wl, *Wr, *Ws, *bl, *bs;
  ushort *Bh, *Bo;
  float* bb;
  int M;
  if (layer == 0) {
    Wl = Wl0; Wr = Wr0; Ws = Ws0; bl = bl0; bs = bs0; Bh = Bh0; Bo = Bo0; bb = bb0; M = 256;
  } else if (layer == 1) {
    Wl = Wl1; Wr = Wr1; Ws = Ws1; bl = bl1; bs = bs1; Bh = Bh1; Bo = Bo1; bb = bb1; M = 256;
  } else {
    Wl = Wl2; Wr = Wr2; Ws = Ws2; bl = bl2; bs = bs2; Bh = Bh2; Bo = Bo2; bb = bb2; M = 128;
  }
  const int DO = M / 2;
  int idx = blockIdx.x * 256 + threadIdx.x;
  if (idx < 128 * M) {
    int k = idx / M, c = idx - k * M;
    float v = (c < DO) ? Wl[k * DO + c] : (Wr[k * DO + (c - DO)] + Ws[k * DO + (c - DO)]);
    unsigned short h = bf16_rne(v);
    unsigned short l = bf16_rne(v - bf16_to_f(h));
    int d = ((k >> 3) * M + c) * 8 + (k & 7);
    Bh[d] = h;
    Bo[d] = l;
  }
  if (idx < DO) bb[idx] = bl[idx] + bs[idx];
}

// ---------------- MFMA GEMM ----------------
__device__ __forceinline__ void split8(const float* __restrict__ p, short8& h, short8& l) {
  float4 f0 = *(const float4*)p;
  float4 f1 = *(const float4*)(p + 4);
  float f[8] = {f0.x, f0.y, f0.z, f0.w, f1.x, f1.y, f1.z, f1.w};
#pragma unroll
  for (int j = 0; j < 8; ++j) {
    unsigned u = __builtin_bit_cast(unsigned, f[j]);
    h[j] = (short)(u >> 16);
    l[j] = (short)bf16_rne(f[j] - bits_to_f(u & 0xffff0000u));
  }
}

template <int M, bool AFP32>
__global__ LB(256, 2) void mfma_gemm_kernel(const float* __restrict__ Af,
                                            const ushort* __restrict__ Ahi,
                                            const ushort* __restrict__ Alo,
                                            const ushort* __restrict__ Bhi,
                                            const ushort* __restrict__ Blo,
                                            ushort* __restrict__ Yb, float* __restrict__ Z, int n) {
  constexpr int DO = M / 2;
  constexpr int NWC = M / 64;
  constexpr int NWR = 4 / NWC;
  const int tid = threadIdx.x;
  const int w = tid >> 6, l = tid & 63;
  const int q = l >> 4, m16 = l & 15;
  const int rowBase = blockIdx.x * (64 * NWR) + (w / NWC) * 64;
  const int colBase = (w % NWC) * 64;

  f32x4 acc[4][4] = {};
  int rrow[4];
#pragma unroll
  for (int i = 0; i < 4; ++i) {
    int r = rowBase + i * 16 + m16;
    rrow[i] = r < n ? r : n - 1;
  }

#pragma unroll
  for (int s = 0; s < 4; ++s) {
    const int ka = s * 32 + q * 8;
    short8 ah[4], al[4], bh[4], bo[4];
#pragma unroll
    for (int i = 0; i < 4; ++i) {
      size_t off = (size_t)rrow[i] * 128 + ka;
      if (AFP32) {
        split8(Af + off, ah[i], al[i]);
      } else {
        ah[i] = *(const short8*)(Ahi + off);
        al[i] = *(const short8*)(Alo + off);
      }
    }
    const int kb = s * 4 + q;
#pragma unroll
    for (int j = 0; j < 4; ++j) {
      size_t off = ((size_t)kb * M + colBase + j * 16 + m16) * 8;
      bh[j] = *(const short8*)(Bhi + off);
      bo[j] = *(const short8*)(Blo + off);
    }
#pragma unroll
    for (int i = 0; i < 4; ++i)
#pragma unroll
      for (int j = 0; j < 4; ++j) {
        acc[i][j] = __builtin_amdgcn_mfma_f32_16x16x32_bf16(ah[i], bh[j], acc[i][j], 0, 0, 0);
        acc[i][j] = __builtin_amdgcn_mfma_f32_16x16x32_bf16(ah[i], bo[j], acc[i][j], 0, 0, 0);
        acc[i][j] = __builtin_amdgcn_mfma_f32_16x16x32_bf16(al[i], bh[j], acc[i][j], 0, 0, 0);
      }
  }

#pragma unroll
  for (int i = 0; i < 4; ++i) {
    int rb = rowBase + i * 16 + q * 4;
#pragma unroll
    for (int j = 0; j < 4; ++j) {
      int c = colBase + j * 16 + m16;
#pragma unroll
      for (int r = 0; r < 4; ++r) {
        int row = rb + r;
        if (row < n) {
          float v = acc[i][j][r];
          if (c < DO)
            Yb[(size_t)row * DO + c] = bf16_rne(v);
          else
            Z[(size_t)row * DO + (c - DO)] = v;
        }
      }
    }
  }
}

// ---------------- aggregation ----------------
// One wave per node. Indices block-loaded once + shfl broadcast.
// ALL __shfl calls under wave-uniform control flow; only the USE is predicated.
__global__ LB(256) void agg128_kernel(const ushort* __restrict__ Y, const float* __restrict__ Z,
                                      const int* __restrict__ row_ptr, const int* __restrict__ srcs,
                                      const float* __restrict__ scale,
                                      const float* __restrict__ bsum, unsigned* __restrict__ Hhi,
                                      unsigned* __restrict__ Hlo, int n) {
  int node = blockIdx.x * 4 + (threadIdx.x >> 6);
  if (node >= n) return;  // wave-uniform exit
  const int lane = threadIdx.x & 63;
  const int li = lane & 31;
  const int half = lane >> 5;
  const int e0 = row_ptr[node], end = row_ptr[node + 1];
  const int cnt = end - e0;
  const int c1 = cnt < 64 ? cnt : 64;
  int idx = (lane < c1) ? srcs[e0 + lane] : 0;
  const uint2* Yu = (const uint2*)Y;  // row = 32 uint2
  float a0 = 0.f, a1 = 0.f, a2 = 0.f, a3 = 0.f;

  int j = 0;
  for (; j + 8 <= c1; j += 8) {
    int s0 = __shfl(idx, j + half);
    int s1 = __shfl(idx, j + 2 + half);
    int s2 = __shfl(idx, j + 4 + half);
    int s3 = __shfl(idx, j + 6 + half);
    uint2 u0 = Yu[(size_t)s0 * 32 + li];
    uint2 u1 = Yu[(size_t)s1 * 32 + li];
    uint2 u2 = Yu[(size_t)s2 * 32 + li];
    uint2 u3 = Yu[(size_t)s3 * 32 + li];
    a0 += bits_to_f(u0.x << 16) + bits_to_f(u1.x << 16) + bits_to_f(u2.x << 16) +
          bits_to_f(u3.x << 16);
    a1 += bits_to_f(u0.x & 0xffff0000u) + bits_to_f(u1.x & 0xffff0000u) +
          bits_to_f(u2.x & 0xffff0000u) + bits_to_f(u3.x & 0xffff0000u);
    a2 += bits_to_f(u0.y << 16) + bits_to_f(u1.y << 16) + bits_to_f(u2.y << 16) +
          bits_to_f(u3.y << 16);
    a3 += bits_to_f(u0.y & 0xffff0000u) + bits_to_f(u1.y & 0xffff0000u) +
          bits_to_f(u2.y & 0xffff0000u) + bits_to_f(u3.y & 0xffff0000u);
  }
  for (; j + 2 <= c1; j += 2) {
    int s = __shfl(idx, j + half);
    uint2 u = Yu[(size_t)s * 32 + li];
    a0 += bits_to_f(u.x << 16);
    a1 += bits_to_f(u.x & 0xffff0000u);
    a2 += bits_to_f(u.y << 16);
    a3 += bits_to_f(u.y & 0xffff0000u);
  }
  if (j < c1) {  // uniform — shfl by ALL lanes, use by half 0 only
    int s = __shfl(idx, j);
    if (half == 0) {
      uint2 u = Yu[(size_t)s * 32 + li];
      a0 += bits_to_f(u.x << 16);
      a1 += bits_to_f(u.x & 0xffff0000u);
      a2 += bits_to_f(u.y << 16);
      a3 += bits_to_f(u.y & 0xffff0000u);
    }
  }
  if (cnt > 64) {
    int e = e0 + 64;
    for (; e + 2 <= end; e += 2) {
      int s = srcs[e + half];
      uint2 u = Yu[(size_t)s * 32 + li];
      a0 += bits_to_f(u.x << 16);
      a1 += bits_to_f(u.x & 0xffff0000u);
      a2 += bits_to_f(u.y << 16);
      a3 += bits_to_f(u.y & 0xffff0000u);
    }
    if (e < end && half == 0) {
      int s = srcs[e];
      uint2 u = Yu[(size_t)s * 32 + li];
      a0 += bits_to_f(u.x << 16);
      a1 += bits_to_f(u.x & 0xffff0000u);
      a2 += bits_to_f(u.y << 16);
      a3 += bits_to_f(u.y & 0xffff0000u);
    }
  }
  a0 += __shfl(a0, lane ^ 32);
  a1 += __shfl(a1, lane ^ 32);
  a2 += __shfl(a2, lane ^ 32);
  a3 += __shfl(a3, lane ^ 32);

  float sc = scale[node];
  float4 z = ((const float4*)Z)[(size_t)node * 32 + li];
  float4 b = ((const float4*)bsum)[li];
  float o0 = fmaxf(z.x + sc * a0 + b.x, 0.f);
  float o1 = fmaxf(z.y + sc * a1 + b.y, 0.f);
  float o2 = fmaxf(z.z + sc * a2 + b.z, 0.f);
  float o3 = fmaxf(z.w + sc * a3 + b.w, 0.f);
  unsigned short h0 = bf16_rne(o0), h1 = bf16_rne(o1), h2 = bf16_rne(o2), h3 = bf16_rne(o3);
  if (half == 0) {
    uint2 hp;
    hp.x = (unsigned)h0 | ((unsigned)h1 << 16);
    hp.y = (unsigned)h2 | ((unsigned)h3 << 16);
    ((uint2*)Hhi)[(size_t)node * 32 + li] = hp;
  } else {
    unsigned short l0 = bf16_rne(o0 - bf16_to_f(h0));
    unsigned short l1 = bf16_rne(o1 - bf16_to_f(h1));
    unsigned short l2 = bf16_rne(o2 - bf16_to_f(h2));
    unsigned short l3 = bf16_rne(o3 - bf16_to_f(h3));
    uint2 lp;
    lp.x = (unsigned)l0 | ((unsigned)l1 << 16);
    lp.y = (unsigned)l2 | ((unsigned)l3 << 16);
    ((uint2*)Hlo)[(size_t)node * 32 + li] = lp;
  }
}

// DO=64 final: quarter-wave (16 lanes x uint2 = 128B) per edge row.
__global__ LB(256) void agg64_kernel(const ushort* __restrict__ Y, const float* __restrict__ Z,
                                     const int* __restrict__ row_ptr, const int* __restrict__ srcs,
                                     const float* __restrict__ scale, const float* __restrict__ bsum,
                                     float* __restrict__ out, int n) {
  int node = blockIdx.x * 4 + (threadIdx.x >> 6);
  if (node >= n) return;  // wave-uniform exit
  const int lane = threadIdx.x & 63;
  const int li = lane & 15;
  const int qt = lane >> 4;
  const int e0 = row_ptr[node], end = row_ptr[node + 1];
  const int cnt = end - e0;
  const int c1 = cnt < 64 ? cnt : 64;
  int idx = (lane < c1) ? srcs[e0 + lane] : 0;
  const uint2* Yu = (const uint2*)Y;  // row = 16 uint2
  float a0 = 0.f, a1 = 0.f, a2 = 0.f, a3 = 0.f;

  int j = 0;
  for (; j + 16 <= c1; j += 16) {
    int s0 = __shfl(idx, j + qt);
    int s1 = __shfl(idx, j + 4 + qt);
    int s2 = __shfl(idx, j + 8 + qt);
    int s3 = __shfl(idx, j + 12 + qt);
    uint2 u0 = Yu[(size_t)s0 * 16 + li];
    uint2 u1 = Yu[(size_t)s1 * 16 + li];
    uint2 u2 = Yu[(size_t)s2 * 16 + li];
    uint2 u3 = Yu[(size_t)s3 * 16 + li];
    a0 += bits_to_f(u0.x << 16) + bits_to_f(u1.x << 16) + bits_to_f(u2.x << 16) +
          bits_to_f(u3.x << 16);
    a1 += bits_to_f(u0.x & 0xffff0000u) + bits_to_f(u1.x & 0xffff0000u) +
          bits_to_f(u2.x & 0xffff0000u) + bits_to_f(u3.x & 0xffff0000u);
    a2 += bits_to_f(u0.y << 16) + bits_to_f(u1.y << 16) + bits_to_f(u2.y << 16) +
          bits_to_f(u3.y << 16);
    a3 += bits_to_f(u0.y & 0xffff0000u) + bits_to_f(u1.y & 0xffff0000u) +
          bits_to_f(u2.y & 0xffff0000u) + bits_to_f(u3.y & 0xffff0000u);
  }
  for (; j + 4 <= c1; j += 4) {
    int s = __shfl(idx, j + qt);
    uint2 u = Yu[(size_t)s * 16 + li];
    a0 += bits_to_f(u.x << 16);
    a1 += bits_to_f(u.x & 0xffff0000u);
    a2 += bits_to_f(u.y << 16);
    a3 += bits_to_f(u.y & 0xffff0000u);
  }
  {
    int rem = c1 - j;
    if (rem > 0) {  // uniform — shfl by ALL lanes, use predicated
      int s = __shfl(idx, j + (qt < rem ? qt : 0));
      if (qt < rem) {
        uint2 u = Yu[(size_t)s * 16 + li];
        a0 += bits_to_f(u.x << 16);
        a1 += bits_to_f(u.x & 0xffff0000u);
        a2 += bits_to_f(u.y << 16);
        a3 += bits_to_f(u.y & 0xffff0000u);
      }
    }
  }
  if (cnt > 64) {
    int e = e0 + 64;
    for (; e + 4 <= end; e += 4) {
      int s = srcs[e + qt];
      uint2 u = Yu[(size_t)s * 16 + li];
      a0 += bits_to_f(u.x << 16);
      a1 += bits_to_f(u.x & 0xffff0000u);
      a2 += bits_to_f(u.y << 16);
      a3 += bits_to_f(u.y & 0xffff0000u);
    }
    int rem = end - e;
    if (qt < rem) {
      int s = srcs[e + qt];
      uint2 u = Yu[(size_t)s * 16 + li];
      a0 += bits_to_f(u.x << 16);
      a1 += bits_to_f(u.x & 0xffff0000u);
      a2 += bits_to_f(u.y << 16);
      a3 += bits_to_f(u.y & 0xffff0000u);
    }
  }
  a0 += __shfl(a0, lane ^ 16);
  a1 += __shfl(a1, lane ^ 16);
  a2 += __shfl(a2, lane ^ 16);
  a3 += __shfl(a3, lane ^ 16);
  a0 += __shfl(a0, lane ^ 32);
  a1 += __shfl(a1, lane ^ 32);
  a2 += __shfl(a2, lane ^ 32);
  a3 += __shfl(a3, lane ^ 32);

  if (qt == 0) {
    float sc = scale[node];
    float4 z = ((const float4*)Z)[(size_t)node * 16 + li];
    float4 b = ((const float4*)bsum)[li];
    float4 o;
    o.x = z.x + sc * a0 + b.x;
    o.y = z.y + sc * a1 + b.y;
    o.z = z.z + sc * a2 + b.z;
    o.w = z.w + sc * a3 + b.w;
    ((float4*)out)[(size_t)node * 16 + li] = o;
  }
}

// ---------------- launch ----------------
extern "C" void kernel_launch(void* const* d_in, const int* in_sizes, int n_in,
                              void* d_out, int out_size, void* d_ws, size_t ws_size,
                              hipStream_t stream) {
  const float* x = (const float*)d_in[0];
  const int* ei = (const int*)d_in[1];
  const int N = in_sizes[0] / 128;
  const int E = in_sizes[3];
  const int* src = ei;
  const int* dst = ei + E;
  const float* Wl[3] = {(const float*)d_in[4], (const float*)d_in[9], (const float*)d_in[14]};
  const float* bl[3] = {(const float*)d_in[5], (const float*)d_in[10], (const float*)d_in[15]};
  const float* Wr[3] = {(const float*)d_in[6], (const float*)d_in[11], (const float*)d_in[16]};
  const float* Ws[3] = {(const float*)d_in[7], (const float*)d_in[12], (const float*)d_in[17]};
  const float* bs[3] = {(const float*)d_in[8], (const float*)d_in[13], (const float*)d_in[18]};

  const int NB = (N + 255) >> 8;

  size_t off = 0;
  auto carve = [&](size_t bytes) -> char* {
    char* p = (char*)d_ws + off;
    off += (bytes + 255) & ~(size_t)255;
    return p;
  };
  int* row_ptr = (int*)carve((size_t)(N + 1) * 4);
  int* bcnt = (int*)carve((size_t)NB * 4);
  unsigned* status = (unsigned*)carve((size_t)NB * 4);
  float* scale = (float*)carve((size_t)N * 4);
  int* srcs = (int*)carve((size_t)E * 4);
  int2* pairs = (int2*)carve((size_t)NB * BCAP * 8);
  ushort* Hhi = (ushort*)carve((size_t)N * 128 * 2);
  ushort* Hlo = (ushort*)carve((size_t)N * 128 * 2);
  ushort* Yb = (ushort*)carve((size_t)N * 128 * 2);
  float* Zf = (float*)carve((size_t)N * 128 * 4);
  ushort* Bh[3];
  ushort* Bo[3];
  float* bsum[3];
  for (int i = 0; i < 3; ++i) {
    Bh[i] = (ushort*)carve(128 * 256 * 2);
    Bo[i] = (ushort*)carve(128 * 256 * 2);
    bsum[i] = (float*)carve(128 * 4);
  }
  (void)ws_size;
  (void)n_in;
  (void)out_size;

  // K1: weights pack + zero bcnt/status (must precede p1)
  wpack_all<<<dim3(128, 3), 256, 0, stream>>>(Wl[0], Wr[0], Ws[0], bl[0], bs[0], Wl[1], Wr[1],
                                              Ws[1], bl[1], bs[1], Wl[2], Wr[2], Ws[2], bl[2],
                                              bs[2], Bh[0], Bo[0], bsum[0], Bh[1], Bo[1], bsum[1],
                                              Bh[2], Bo[2], bsum[2], bcnt, status, NB);
  // K2: bucket partition
  p1_bucket<<<(E + P1_CHUNK - 1) / P1_CHUNK, 256, 0, stream>>>(src, dst, bcnt, pairs, E);
  // K3: hist + scan (decoupled lookback) + place
  p234_kernel<<<NB, 256, 0, stream>>>(pairs, bcnt, status, row_ptr, scale, srcs, N, NB);

  int g64 = (N + 63) / 64;
  int g128 = (N + 127) / 128;
  int gAgg = (N + 3) / 4;

  // layer 0 (A = fp32 x, split in-reg)
  mfma_gemm_kernel<256, true><<<g64, 256, 0, stream>>>(x, nullptr, nullptr, Bh[0], Bo[0], Yb, Zf, N);
  agg128_kernel<<<gAgg, 256, 0, stream>>>(Yb, Zf, row_ptr, srcs, scale, bsum[0], (unsigned*)Hhi,
                                          (unsigned*)Hlo, N);
  // layer 1
  mfma_gemm_kernel<256, false><<<g64, 256, 0, stream>>>(nullptr, Hhi, Hlo, Bh[1], Bo[1], Yb, Zf, N);
  agg128_kernel<<<gAgg, 256, 0, stream>>>(Yb, Zf, row_ptr, srcs, scale, bsum[1], (unsigned*)Hhi,
                                          (unsigned*)Hlo, N);
  // layer 2
  mfma_gemm_kernel<128, false><<<g128, 256, 0, stream>>>(nullptr, Hhi, Hlo, Bh[2], Bo[2], Yb, Zf, N);
  agg64_kernel<<<gAgg, 256, 0, stream>>>(Yb, Zf, row_ptr, srcs, scale, bsum[2], (float*)d_out, N);
}

// Round 8
// 334.571 us; speedup vs baseline: 1.1240x; 1.1240x over previous
//
#include <hip/hip_runtime.h>
#include <hip/hip_bf16.h>

// GNNEncoder: 3-layer GraphSAGE (mean agg), N=50000, E=800000.
// h' = act( mean_agg(x@Wl) + x@(Wr+Ws) + (bl+bs) )   (matmul-first by linearity)
// R8: p234 lookback (serial 57µs spin) replaced by ONE atomicAdd region-claim:
//     buckets get srcs regions in arrival order; per-node (row_start, deg)
//     arrays replace monotonic row_ptr. agg128 burst deepened to 16 edges.

#define LB __launch_bounds__

typedef __attribute__((ext_vector_type(8))) short short8;
typedef __attribute__((ext_vector_type(4))) float f32x4;

__device__ __forceinline__ unsigned short bf16_rne(float f) {
  unsigned u = __builtin_bit_cast(unsigned, f);
  unsigned r = u + 0x7fffu + ((u >> 16) & 1u);
  return (unsigned short)(r >> 16);
}
__device__ __forceinline__ float bf16_to_f(unsigned short us) {
  return __builtin_bit_cast(float, (unsigned)us << 16);
}
__device__ __forceinline__ float bits_to_f(unsigned u) {
  return __builtin_bit_cast(float, u);
}

// ---------------- CSR build: bucketed 2-pass sort ----------------
#define BCAP 8192
#define P1_CHUNK 4096

__global__ LB(256) void p1_bucket(const int* __restrict__ src, const int* __restrict__ dst,
                                  int* __restrict__ bcnt, int2* __restrict__ pairs, int E) {
  __shared__ int cnt[256];
  __shared__ int base[256];
  const int tid = threadIdx.x;
  cnt[tid] = 0;
  __syncthreads();
  const int e0 = blockIdx.x * P1_CHUNK;
  int myb[16], myr[16], mys[16], myd[16];
#pragma unroll
  for (int i = 0; i < 16; ++i) {
    int e = e0 + i * 256 + tid;
    myb[i] = -1;
    if (e < E) {
      int s = src[e], d = dst[e];
      int b = d >> 8;
      myb[i] = b;
      mys[i] = s;
      myd[i] = d;
      myr[i] = atomicAdd(&cnt[b], 1);
    }
  }
  __syncthreads();
  base[tid] = (cnt[tid] > 0) ? atomicAdd(&bcnt[tid], cnt[tid]) : 0;
  __syncthreads();
#pragma unroll
  for (int i = 0; i < 16; ++i) {
    int b = myb[i];
    if (b >= 0) {
      int p = base[b] + myr[i];
      if (p < BCAP) pairs[(size_t)b * BCAP + p] = make_int2(mys[i], myd[i]);
    }
  }
}

// Fused: per-bucket hist + local scan + ONE atomicAdd to claim a srcs region
// (arrival order — valid because agg uses explicit row_start/deg, not a
// monotonic row_ptr) + edge placement + scale. No inter-block waiting.
__global__ LB(256) void p234_kernel(const int2* __restrict__ pairs, const int* __restrict__ bcnt,
                                    int* __restrict__ gcounter, int* __restrict__ row_start,
                                    int* __restrict__ deg_arr, float* __restrict__ scale,
                                    int* __restrict__ srcs, int N) {
  __shared__ int h[256];
  __shared__ int sc[256];
  __shared__ int cur[256];
  __shared__ int shared_bb;
  const int tid = threadIdx.x;
  const int b = blockIdx.x;
  h[tid] = 0;
  __syncthreads();
  int m = bcnt[b];
  if (m > BCAP) m = BCAP;
  for (int i = tid; i < m; i += 256) {
    atomicAdd(&h[pairs[(size_t)b * BCAP + i].y & 255], 1);
  }
  __syncthreads();
  const int deg = h[tid];
  sc[tid] = deg;
  __syncthreads();
  for (int off = 1; off < 256; off <<= 1) {
    int add = (tid >= off) ? sc[tid - off] : 0;
    __syncthreads();
    sc[tid] += add;
    __syncthreads();
  }
  if (tid == 0) shared_bb = atomicAdd(gcounter, sc[255]);
  __syncthreads();
  const int abs_off = shared_bb + sc[tid] - deg;
  const int node = b * 256 + tid;
  if (node < N) {
    row_start[node] = abs_off;
    deg_arr[node] = deg;
    scale[node] = 1.0f / (float)(deg > 1 ? deg : 1);
  }
  cur[tid] = abs_off;
  __syncthreads();
  for (int i = tid; i < m; i += 256) {
    int2 pr = pairs[(size_t)b * BCAP + i];
    int p = atomicAdd(&cur[pr.y & 255], 1);
    srcs[p] = pr.x;
  }
}

// ---------------- weights -> fragment-ordered hi/lo bf16 + bias; zeroes bcnt/gcounter ----
__global__ LB(256) void wpack_all(const float* __restrict__ Wl0, const float* __restrict__ Wr0,
                                  const float* __restrict__ Ws0, const float* __restrict__ bl0,
                                  const float* __restrict__ bs0, const float* __restrict__ Wl1,
                                  const float* __restrict__ Wr1, const float* __restrict__ Ws1,
                                  const float* __restrict__ bl1, const float* __restrict__ bs1,
                                  const float* __restrict__ Wl2, const float* __restrict__ Wr2,
                                  const float* __restrict__ Ws2, const float* __restrict__ bl2,
                                  const float* __restrict__ bs2, ushort* __restrict__ Bh0,
                                  ushort* __restrict__ Bo0, float* __restrict__ bb0,
                                  ushort* __restrict__ Bh1, ushort* __restrict__ Bo1,
                                  float* __restrict__ bb1, ushort* __restrict__ Bh2,
                                  ushort* __restrict__ Bo2, float* __restrict__ bb2,
                                  int* __restrict__ bcnt, int* __restrict__ gcounter, int NB) {
  const int layer = blockIdx.y;
  if (layer == 0 && blockIdx.x == 0) {
    for (int i = threadIdx.x; i < NB; i += 256) bcnt[i] = 0;
    if (threadIdx.x == 0) *gcounter = 0;
  }
  const float *Wl, *Wr, *Ws, *bl, *bs;
  ushort *Bh, *Bo;
  float* bb;
  int M;
  if (layer == 0) {
    Wl = Wl0; Wr = Wr0; Ws = Ws0; bl = bl0; bs = bs0; Bh = Bh0; Bo = Bo0; bb = bb0; M = 256;
  } else if (layer == 1) {
    Wl = Wl1; Wr = Wr1; Ws = Ws1; bl = bl1; bs = bs1; Bh = Bh1; Bo = Bo1; bb = bb1; M = 256;
  } else {
    Wl = Wl2; Wr = Wr2; Ws = Ws2; bl = bl2; bs = bs2; Bh = Bh2; Bo = Bo2; bb = bb2; M = 128;
  }
  const int DO = M / 2;
  int idx = blockIdx.x * 256 + threadIdx.x;
  if (idx < 128 * M) {
    int k = idx / M, c = idx - k * M;
    float v = (c < DO) ? Wl[k * DO + c] : (Wr[k * DO + (c - DO)] + Ws[k * DO + (c - DO)]);
    unsigned short h = bf16_rne(v);
    unsigned short l = bf16_rne(v - bf16_to_f(h));
    int d = ((k >> 3) * M + c) * 8 + (k & 7);
    Bh[d] = h;
    Bo[d] = l;
  }
  if (idx < DO) bb[idx] = bl[idx] + bs[idx];
}

// ---------------- MFMA GEMM ----------------
__device__ __forceinline__ void split8(const float* __restrict__ p, short8& h, short8& l) {
  float4 f0 = *(const float4*)p;
  float4 f1 = *(const float4*)(p + 4);
  float f[8] = {f0.x, f0.y, f0.z, f0.w, f1.x, f1.y, f1.z, f1.w};
#pragma unroll
  for (int j = 0; j < 8; ++j) {
    unsigned u = __builtin_bit_cast(unsigned, f[j]);
    h[j] = (short)(u >> 16);
    l[j] = (short)bf16_rne(f[j] - bits_to_f(u & 0xffff0000u));
  }
}

template <int M, bool AFP32>
__global__ LB(256, 2) void mfma_gemm_kernel(const float* __restrict__ Af,
                                            const ushort* __restrict__ Ahi,
                                            const ushort* __restrict__ Alo,
                                            const ushort* __restrict__ Bhi,
                                            const ushort* __restrict__ Blo,
                                            ushort* __restrict__ Yb, float* __restrict__ Z, int n) {
  constexpr int DO = M / 2;
  constexpr int NWC = M / 64;
  constexpr int NWR = 4 / NWC;
  const int tid = threadIdx.x;
  const int w = tid >> 6, l = tid & 63;
  const int q = l >> 4, m16 = l & 15;
  const int rowBase = blockIdx.x * (64 * NWR) + (w / NWC) * 64;
  const int colBase = (w % NWC) * 64;

  f32x4 acc[4][4] = {};
  int rrow[4];
#pragma unroll
  for (int i = 0; i < 4; ++i) {
    int r = rowBase + i * 16 + m16;
    rrow[i] = r < n ? r : n - 1;
  }

#pragma unroll
  for (int s = 0; s < 4; ++s) {
    const int ka = s * 32 + q * 8;
    short8 ah[4], al[4], bh[4], bo[4];
#pragma unroll
    for (int i = 0; i < 4; ++i) {
      size_t off = (size_t)rrow[i] * 128 + ka;
      if (AFP32) {
        split8(Af + off, ah[i], al[i]);
      } else {
        ah[i] = *(const short8*)(Ahi + off);
        al[i] = *(const short8*)(Alo + off);
      }
    }
    const int kb = s * 4 + q;
#pragma unroll
    for (int j = 0; j < 4; ++j) {
      size_t off = ((size_t)kb * M + colBase + j * 16 + m16) * 8;
      bh[j] = *(const short8*)(Bhi + off);
      bo[j] = *(const short8*)(Blo + off);
    }
#pragma unroll
    for (int i = 0; i < 4; ++i)
#pragma unroll
      for (int j = 0; j < 4; ++j) {
        acc[i][j] = __builtin_amdgcn_mfma_f32_16x16x32_bf16(ah[i], bh[j], acc[i][j], 0, 0, 0);
        acc[i][j] = __builtin_amdgcn_mfma_f32_16x16x32_bf16(ah[i], bo[j], acc[i][j], 0, 0, 0);
        acc[i][j] = __builtin_amdgcn_mfma_f32_16x16x32_bf16(al[i], bh[j], acc[i][j], 0, 0, 0);
      }
  }

#pragma unroll
  for (int i = 0; i < 4; ++i) {
    int rb = rowBase + i * 16 + q * 4;
#pragma unroll
    for (int j = 0; j < 4; ++j) {
      int c = colBase + j * 16 + m16;
#pragma unroll
      for (int r = 0; r < 4; ++r) {
        int row = rb + r;
        if (row < n) {
          float v = acc[i][j][r];
          if (c < DO)
            Yb[(size_t)row * DO + c] = bf16_rne(v);
          else
            Z[(size_t)row * DO + (c - DO)] = v;
        }
      }
    }
  }
}

// ---------------- aggregation ----------------
// One wave per node; (row_start, deg) arrays; indices block-loaded + shfl.
// All __shfl under wave-uniform control flow; only USES are predicated.
__global__ LB(256) void agg128_kernel(const ushort* __restrict__ Y, const float* __restrict__ Z,
                                      const int* __restrict__ row_start,
                                      const int* __restrict__ deg_arr, const int* __restrict__ srcs,
                                      const float* __restrict__ scale,
                                      const float* __restrict__ bsum, unsigned* __restrict__ Hhi,
                                      unsigned* __restrict__ Hlo, int n) {
  int node = blockIdx.x * 4 + (threadIdx.x >> 6);
  if (node >= n) return;  // wave-uniform exit
  const int lane = threadIdx.x & 63;
  const int li = lane & 31;
  const int half = lane >> 5;
  const int e0 = row_start[node];
  const int cnt = deg_arr[node];
  const int end = e0 + cnt;
  const int c1 = cnt < 64 ? cnt : 64;
  int idx = (lane < c1) ? srcs[e0 + lane] : 0;
  const uint2* Yu = (const uint2*)Y;  // row = 32 uint2
  float a0 = 0.f, a1 = 0.f, a2 = 0.f, a3 = 0.f;

  int j = 0;
  for (; j + 16 <= c1; j += 16) {  // 8 loads in flight
    int s[8];
#pragma unroll
    for (int t = 0; t < 8; ++t) s[t] = __shfl(idx, j + 2 * t + half);
    uint2 u[8];
#pragma unroll
    for (int t = 0; t < 8; ++t) u[t] = Yu[(size_t)s[t] * 32 + li];
#pragma unroll
    for (int t = 0; t < 8; ++t) {
      a0 += bits_to_f(u[t].x << 16);
      a1 += bits_to_f(u[t].x & 0xffff0000u);
      a2 += bits_to_f(u[t].y << 16);
      a3 += bits_to_f(u[t].y & 0xffff0000u);
    }
  }
  if (j + 8 <= c1) {
    int s[4];
#pragma unroll
    for (int t = 0; t < 4; ++t) s[t] = __shfl(idx, j + 2 * t + half);
    uint2 u[4];
#pragma unroll
    for (int t = 0; t < 4; ++t) u[t] = Yu[(size_t)s[t] * 32 + li];
#pragma unroll
    for (int t = 0; t < 4; ++t) {
      a0 += bits_to_f(u[t].x << 16);
      a1 += bits_to_f(u[t].x & 0xffff0000u);
      a2 += bits_to_f(u[t].y << 16);
      a3 += bits_to_f(u[t].y & 0xffff0000u);
    }
    j += 8;
  }
  for (; j + 2 <= c1; j += 2) {
    int s = __shfl(idx, j + half);
    uint2 u = Yu[(size_t)s * 32 + li];
    a0 += bits_to_f(u.x << 16);
    a1 += bits_to_f(u.x & 0xffff0000u);
    a2 += bits_to_f(u.y << 16);
    a3 += bits_to_f(u.y & 0xffff0000u);
  }
  if (j < c1) {  // uniform — shfl by ALL lanes, use by half 0 only
    int s = __shfl(idx, j);
    if (half == 0) {
      uint2 u = Yu[(size_t)s * 32 + li];
      a0 += bits_to_f(u.x << 16);
      a1 += bits_to_f(u.x & 0xffff0000u);
      a2 += bits_to_f(u.y << 16);
      a3 += bits_to_f(u.y & 0xffff0000u);
    }
  }
  if (cnt > 64) {
    int e = e0 + 64;
    for (; e + 2 <= end; e += 2) {
      int s = srcs[e + half];
      uint2 u = Yu[(size_t)s * 32 + li];
      a0 += bits_to_f(u.x << 16);
      a1 += bits_to_f(u.x & 0xffff0000u);
      a2 += bits_to_f(u.y << 16);
      a3 += bits_to_f(u.y & 0xffff0000u);
    }
    if (e < end && half == 0) {
      int s = srcs[e];
      uint2 u = Yu[(size_t)s * 32 + li];
      a0 += bits_to_f(u.x << 16);
      a1 += bits_to_f(u.x & 0xffff0000u);
      a2 += bits_to_f(u.y << 16);
      a3 += bits_to_f(u.y & 0xffff0000u);
    }
  }
  a0 += __shfl(a0, lane ^ 32);
  a1 += __shfl(a1, lane ^ 32);
  a2 += __shfl(a2, lane ^ 32);
  a3 += __shfl(a3, lane ^ 32);

  float sc = scale[node];
  float4 z = ((const float4*)Z)[(size_t)node * 32 + li];
  float4 b = ((const float4*)bsum)[li];
  float o0 = fmaxf(z.x + sc * a0 + b.x, 0.f);
  float o1 = fmaxf(z.y + sc * a1 + b.y, 0.f);
  float o2 = fmaxf(z.z + sc * a2 + b.z, 0.f);
  float o3 = fmaxf(z.w + sc * a3 + b.w, 0.f);
  unsigned short h0 = bf16_rne(o0), h1 = bf16_rne(o1), h2 = bf16_rne(o2), h3 = bf16_rne(o3);
  if (half == 0) {
    uint2 hp;
    hp.x = (unsigned)h0 | ((unsigned)h1 << 16);
    hp.y = (unsigned)h2 | ((unsigned)h3 << 16);
    ((uint2*)Hhi)[(size_t)node * 32 + li] = hp;
  } else {
    unsigned short l0 = bf16_rne(o0 - bf16_to_f(h0));
    unsigned short l1 = bf16_rne(o1 - bf16_to_f(h1));
    unsigned short l2 = bf16_rne(o2 - bf16_to_f(h2));
    unsigned short l3 = bf16_rne(o3 - bf16_to_f(h3));
    uint2 lp;
    lp.x = (unsigned)l0 | ((unsigned)l1 << 16);
    lp.y = (unsigned)l2 | ((unsigned)l3 << 16);
    ((uint2*)Hlo)[(size_t)node * 32 + li] = lp;
  }
}

// DO=64 final: quarter-wave (16 lanes x uint2 = 128B) per edge row.
__global__ LB(256) void agg64_kernel(const ushort* __restrict__ Y, const float* __restrict__ Z,
                                     const int* __restrict__ row_start,
                                     const int* __restrict__ deg_arr, const int* __restrict__ srcs,
                                     const float* __restrict__ scale, const float* __restrict__ bsum,
                                     float* __restrict__ out, int n) {
  int node = blockIdx.x * 4 + (threadIdx.x >> 6);
  if (node >= n) return;  // wave-uniform exit
  const int lane = threadIdx.x & 63;
  const int li = lane & 15;
  const int qt = lane >> 4;
  const int e0 = row_start[node];
  const int cnt = deg_arr[node];
  const int end = e0 + cnt;
  const int c1 = cnt < 64 ? cnt : 64;
  int idx = (lane < c1) ? srcs[e0 + lane] : 0;
  const uint2* Yu = (const uint2*)Y;  // row = 16 uint2
  float a0 = 0.f, a1 = 0.f, a2 = 0.f, a3 = 0.f;

  int j = 0;
  for (; j + 16 <= c1; j += 16) {
    int s0 = __shfl(idx, j + qt);
    int s1 = __shfl(idx, j + 4 + qt);
    int s2 = __shfl(idx, j + 8 + qt);
    int s3 = __shfl(idx, j + 12 + qt);
    uint2 u0 = Yu[(size_t)s0 * 16 + li];
    uint2 u1 = Yu[(size_t)s1 * 16 + li];
    uint2 u2 = Yu[(size_t)s2 * 16 + li];
    uint2 u3 = Yu[(size_t)s3 * 16 + li];
    a0 += bits_to_f(u0.x << 16) + bits_to_f(u1.x << 16) + bits_to_f(u2.x << 16) +
          bits_to_f(u3.x << 16);
    a1 += bits_to_f(u0.x & 0xffff0000u) + bits_to_f(u1.x & 0xffff0000u) +
          bits_to_f(u2.x & 0xffff0000u) + bits_to_f(u3.x & 0xffff0000u);
    a2 += bits_to_f(u0.y << 16) + bits_to_f(u1.y << 16) + bits_to_f(u2.y << 16) +
          bits_to_f(u3.y << 16);
    a3 += bits_to_f(u0.y & 0xffff0000u) + bits_to_f(u1.y & 0xffff0000u) +
          bits_to_f(u2.y & 0xffff0000u) + bits_to_f(u3.y & 0xffff0000u);
  }
  for (; j + 4 <= c1; j += 4) {
    int s = __shfl(idx, j + qt);
    uint2 u = Yu[(size_t)s * 16 + li];
    a0 += bits_to_f(u.x << 16);
    a1 += bits_to_f(u.x & 0xffff0000u);
    a2 += bits_to_f(u.y << 16);
    a3 += bits_to_f(u.y & 0xffff0000u);
  }
  {
    int rem = c1 - j;
    if (rem > 0) {  // uniform — shfl by ALL lanes, use predicated
      int s = __shfl(idx, j + (qt < rem ? qt : 0));
      if (qt < rem) {
        uint2 u = Yu[(size_t)s * 16 + li];
        a0 += bits_to_f(u.x << 16);
        a1 += bits_to_f(u.x & 0xffff0000u);
        a2 += bits_to_f(u.y << 16);
        a3 += bits_to_f(u.y & 0xffff0000u);
      }
    }
  }
  if (cnt > 64) {
    int e = e0 + 64;
    for (; e + 4 <= end; e += 4) {
      int s = srcs[e + qt];
      uint2 u = Yu[(size_t)s * 16 + li];
      a0 += bits_to_f(u.x << 16);
      a1 += bits_to_f(u.x & 0xffff0000u);
      a2 += bits_to_f(u.y << 16);
      a3 += bits_to_f(u.y & 0xffff0000u);
    }
    int rem = end - e;
    if (qt < rem) {
      int s = srcs[e + qt];
      uint2 u = Yu[(size_t)s * 16 + li];
      a0 += bits_to_f(u.x << 16);
      a1 += bits_to_f(u.x & 0xffff0000u);
      a2 += bits_to_f(u.y << 16);
      a3 += bits_to_f(u.y & 0xffff0000u);
    }
  }
  a0 += __shfl(a0, lane ^ 16);
  a1 += __shfl(a1, lane ^ 16);
  a2 += __shfl(a2, lane ^ 16);
  a3 += __shfl(a3, lane ^ 16);
  a0 += __shfl(a0, lane ^ 32);
  a1 += __shfl(a1, lane ^ 32);
  a2 += __shfl(a2, lane ^ 32);
  a3 += __shfl(a3, lane ^ 32);

  if (qt == 0) {
    float sc = scale[node];
    float4 z = ((const float4*)Z)[(size_t)node * 16 + li];
    float4 b = ((const float4*)bsum)[li];
    float4 o;
    o.x = z.x + sc * a0 + b.x;
    o.y = z.y + sc * a1 + b.y;
    o.z = z.z + sc * a2 + b.z;
    o.w = z.w + sc * a3 + b.w;
    ((float4*)out)[(size_t)node * 16 + li] = o;
  }
}

// ---------------- launch ----------------
extern "C" void kernel_launch(void* const* d_in, const int* in_sizes, int n_in,
                              void* d_out, int out_size, void* d_ws, size_t ws_size,
                              hipStream_t stream) {
  const float* x = (const float*)d_in[0];
  const int* ei = (const int*)d_in[1];
  const int N = in_sizes[0] / 128;
  const int E = in_sizes[3];
  const int* src = ei;
  const int* dst = ei + E;
  const float* Wl[3] = {(const float*)d_in[4], (const float*)d_in[9], (const float*)d_in[14]};
  const float* bl[3] = {(const float*)d_in[5], (const float*)d_in[10], (const float*)d_in[15]};
  const float* Wr[3] = {(const float*)d_in[6], (const float*)d_in[11], (const float*)d_in[16]};
  const float* Ws[3] = {(const float*)d_in[7], (const float*)d_in[12], (const float*)d_in[17]};
  const float* bs[3] = {(const float*)d_in[8], (const float*)d_in[13], (const float*)d_in[18]};

  const int NB = (N + 255) >> 8;

  size_t off = 0;
  auto carve = [&](size_t bytes) -> char* {
    char* p = (char*)d_ws + off;
    off += (bytes + 255) & ~(size_t)255;
    return p;
  };
  int* row_start = (int*)carve((size_t)N * 4);
  int* deg_arr = (int*)carve((size_t)N * 4);
  int* bcnt = (int*)carve((size_t)NB * 4);
  int* gcounter = (int*)carve(256);
  float* scale = (float*)carve((size_t)N * 4);
  int* srcs = (int*)carve((size_t)E * 4);
  int2* pairs = (int2*)carve((size_t)NB * BCAP * 8);
  ushort* Hhi = (ushort*)carve((size_t)N * 128 * 2);
  ushort* Hlo = (ushort*)carve((size_t)N * 128 * 2);
  ushort* Yb = (ushort*)carve((size_t)N * 128 * 2);
  float* Zf = (float*)carve((size_t)N * 128 * 4);
  ushort* Bh[3];
  ushort* Bo[3];
  float* bsum[3];
  for (int i = 0; i < 3; ++i) {
    Bh[i] = (ushort*)carve(128 * 256 * 2);
    Bo[i] = (ushort*)carve(128 * 256 * 2);
    bsum[i] = (float*)carve(128 * 4);
  }
  (void)ws_size;
  (void)n_in;
  (void)out_size;

  // K1: weights pack + zero bcnt/gcounter (must precede p1)
  wpack_all<<<dim3(128, 3), 256, 0, stream>>>(Wl[0], Wr[0], Ws[0], bl[0], bs[0], Wl[1], Wr[1],
                                              Ws[1], bl[1], bs[1], Wl[2], Wr[2], Ws[2], bl[2],
                                              bs[2], Bh[0], Bo[0], bsum[0], Bh[1], Bo[1], bsum[1],
                                              Bh[2], Bo[2], bsum[2], bcnt, gcounter, NB);
  // K2: bucket partition
  p1_bucket<<<(E + P1_CHUNK - 1) / P1_CHUNK, 256, 0, stream>>>(src, dst, bcnt, pairs, E);
  // K3: hist + scan + region-claim + place (no inter-block waits)
  p234_kernel<<<NB, 256, 0, stream>>>(pairs, bcnt, gcounter, row_start, deg_arr, scale, srcs, N);

  int g64 = (N + 63) / 64;
  int g128 = (N + 127) / 128;
  int gAgg = (N + 3) / 4;

  // layer 0 (A = fp32 x, split in-reg)
  mfma_gemm_kernel<256, true><<<g64, 256, 0, stream>>>(x, nullptr, nullptr, Bh[0], Bo[0], Yb, Zf, N);
  agg128_kernel<<<gAgg, 256, 0, stream>>>(Yb, Zf, row_start, deg_arr, srcs, scale, bsum[0],
                                          (unsigned*)Hhi, (unsigned*)Hlo, N);
  // layer 1
  mfma_gemm_kernel<256, false><<<g64, 256, 0, stream>>>(nullptr, Hhi, Hlo, Bh[1], Bo[1], Yb, Zf, N);
  agg128_kernel<<<gAgg, 256, 0, stream>>>(Yb, Zf, row_start, deg_arr, srcs, scale, bsum[1],
                                          (unsigned*)Hhi, (unsigned*)Hlo, N);
  // layer 2
  mfma_gemm_kernel<128, false><<<g128, 256, 0, stream>>>(nullptr, Hhi, Hlo, Bh[2], Bo[2], Yb, Zf, N);
  agg64_kernel<<<gAgg, 256, 0, stream>>>(Yb, Zf, row_start, deg_arr, srcs, scale, bsum[2],
                                         (float*)d_out, N);
}

// Round 9
// 328.347 us; speedup vs baseline: 1.1454x; 1.0190x over previous
//
#include <hip/hip_runtime.h>
#include <hip/hip_bf16.h>

// GNNEncoder: 3-layer GraphSAGE (mean agg), N=50000, E=800000.
// h' = act( mean_agg(x@Wl) + x@(Wr+Ws) + (bl+bs) )   (matmul-first by linearity)
// R9: GEMM re-tiled for TLP — wave tile 32x64 (was 64x64), 2x blocks,
//     LB(256,4). R8 profile: MfmaUtil 6%, Occ 24% -> latency-bound on L2/L3
//     loads with too few waves/CU. CSR (R8 region-claim) + agg unchanged.

#define LB __launch_bounds__

typedef __attribute__((ext_vector_type(8))) short short8;
typedef __attribute__((ext_vector_type(4))) float f32x4;

__device__ __forceinline__ unsigned short bf16_rne(float f) {
  unsigned u = __builtin_bit_cast(unsigned, f);
  unsigned r = u + 0x7fffu + ((u >> 16) & 1u);
  return (unsigned short)(r >> 16);
}
__device__ __forceinline__ float bf16_to_f(unsigned short us) {
  return __builtin_bit_cast(float, (unsigned)us << 16);
}
__device__ __forceinline__ float bits_to_f(unsigned u) {
  return __builtin_bit_cast(float, u);
}

// ---------------- CSR build: bucketed 2-pass sort ----------------
#define BCAP 8192
#define P1_CHUNK 4096

__global__ LB(256) void p1_bucket(const int* __restrict__ src, const int* __restrict__ dst,
                                  int* __restrict__ bcnt, int2* __restrict__ pairs, int E) {
  __shared__ int cnt[256];
  __shared__ int base[256];
  const int tid = threadIdx.x;
  cnt[tid] = 0;
  __syncthreads();
  const int e0 = blockIdx.x * P1_CHUNK;
  int myb[16], myr[16], mys[16], myd[16];
#pragma unroll
  for (int i = 0; i < 16; ++i) {
    int e = e0 + i * 256 + tid;
    myb[i] = -1;
    if (e < E) {
      int s = src[e], d = dst[e];
      int b = d >> 8;
      myb[i] = b;
      mys[i] = s;
      myd[i] = d;
      myr[i] = atomicAdd(&cnt[b], 1);
    }
  }
  __syncthreads();
  base[tid] = (cnt[tid] > 0) ? atomicAdd(&bcnt[tid], cnt[tid]) : 0;
  __syncthreads();
#pragma unroll
  for (int i = 0; i < 16; ++i) {
    int b = myb[i];
    if (b >= 0) {
      int p = base[b] + myr[i];
      if (p < BCAP) pairs[(size_t)b * BCAP + p] = make_int2(mys[i], myd[i]);
    }
  }
}

// Fused: per-bucket hist + local scan + ONE atomicAdd region-claim + place.
__global__ LB(256) void p234_kernel(const int2* __restrict__ pairs, const int* __restrict__ bcnt,
                                    int* __restrict__ gcounter, int* __restrict__ row_start,
                                    int* __restrict__ deg_arr, float* __restrict__ scale,
                                    int* __restrict__ srcs, int N) {
  __shared__ int h[256];
  __shared__ int sc[256];
  __shared__ int cur[256];
  __shared__ int shared_bb;
  const int tid = threadIdx.x;
  const int b = blockIdx.x;
  h[tid] = 0;
  __syncthreads();
  int m = bcnt[b];
  if (m > BCAP) m = BCAP;
  for (int i = tid; i < m; i += 256) {
    atomicAdd(&h[pairs[(size_t)b * BCAP + i].y & 255], 1);
  }
  __syncthreads();
  const int deg = h[tid];
  sc[tid] = deg;
  __syncthreads();
  for (int off = 1; off < 256; off <<= 1) {
    int add = (tid >= off) ? sc[tid - off] : 0;
    __syncthreads();
    sc[tid] += add;
    __syncthreads();
  }
  if (tid == 0) shared_bb = atomicAdd(gcounter, sc[255]);
  __syncthreads();
  const int abs_off = shared_bb + sc[tid] - deg;
  const int node = b * 256 + tid;
  if (node < N) {
    row_start[node] = abs_off;
    deg_arr[node] = deg;
    scale[node] = 1.0f / (float)(deg > 1 ? deg : 1);
  }
  cur[tid] = abs_off;
  __syncthreads();
  for (int i = tid; i < m; i += 256) {
    int2 pr = pairs[(size_t)b * BCAP + i];
    int p = atomicAdd(&cur[pr.y & 255], 1);
    srcs[p] = pr.x;
  }
}

// ---------------- weights -> fragment-ordered hi/lo bf16 + bias; zeroes bcnt/gcounter ----
__global__ LB(256) void wpack_all(const float* __restrict__ Wl0, const float* __restrict__ Wr0,
                                  const float* __restrict__ Ws0, const float* __restrict__ bl0,
                                  const float* __restrict__ bs0, const float* __restrict__ Wl1,
                                  const float* __restrict__ Wr1, const float* __restrict__ Ws1,
                                  const float* __restrict__ bl1, const float* __restrict__ bs1,
                                  const float* __restrict__ Wl2, const float* __restrict__ Wr2,
                                  const float* __restrict__ Ws2, const float* __restrict__ bl2,
                                  const float* __restrict__ bs2, ushort* __restrict__ Bh0,
                                  ushort* __restrict__ Bo0, float* __restrict__ bb0,
                                  ushort* __restrict__ Bh1, ushort* __restrict__ Bo1,
                                  float* __restrict__ bb1, ushort* __restrict__ Bh2,
                                  ushort* __restrict__ Bo2, float* __restrict__ bb2,
                                  int* __restrict__ bcnt, int* __restrict__ gcounter, int NB) {
  const int layer = blockIdx.y;
  if (layer == 0 && blockIdx.x == 0) {
    for (int i = threadIdx.x; i < NB; i += 256) bcnt[i] = 0;
    if (threadIdx.x == 0) *gcounter = 0;
  }
  const float *Wl, *Wr, *Ws, *bl, *bs;
  ushort *Bh, *Bo;
  float* bb;
  int M;
  if (layer == 0) {
    Wl = Wl0; Wr = Wr0; Ws = Ws0; bl = bl0; bs = bs0; Bh = Bh0; Bo = Bo0; bb = bb0; M = 256;
  } else if (layer == 1) {
    Wl = Wl1; Wr = Wr1; Ws = Ws1; bl = bl1; bs = bs1; Bh = Bh1; Bo = Bo1; bb = bb1; M = 256;
  } else {
    Wl = Wl2; Wr = Wr2; Ws = Ws2; bl = bl2; bs = bs2; Bh = Bh2; Bo = Bo2; bb = bb2; M = 128;
  }
  const int DO = M / 2;
  int idx = blockIdx.x * 256 + threadIdx.x;
  if (idx < 128 * M) {
    int k = idx / M, c = idx - k * M;
    float v = (c < DO) ? Wl[k * DO + c] : (Wr[k * DO + (c - DO)] + Ws[k * DO + (c - DO)]);
    unsigned short h = bf16_rne(v);
    unsigned short l = bf16_rne(v - bf16_to_f(h));
    int d = ((k >> 3) * M + c) * 8 + (k & 7);
    Bh[d] = h;
    Bo[d] = l;
  }
  if (idx < DO) bb[idx] = bl[idx] + bs[idx];
}

// ---------------- MFMA GEMM ----------------
__device__ __forceinline__ void split8(const float* __restrict__ p, short8& h, short8& l) {
  float4 f0 = *(const float4*)p;
  float4 f1 = *(const float4*)(p + 4);
  float f[8] = {f0.x, f0.y, f0.z, f0.w, f1.x, f1.y, f1.z, f1.w};
#pragma unroll
  for (int j = 0; j < 8; ++j) {
    unsigned u = __builtin_bit_cast(unsigned, f[j]);
    h[j] = (short)(u >> 16);
    l[j] = (short)bf16_rne(f[j] - bits_to_f(u & 0xffff0000u));
  }
}

// Wave tile 32x64 (acc 2x4). M=256: 4 col-waves, block 32x256, grid=(N+31)/32.
// M=128: 2x2 waves, block 64x128, grid=(N+63)/64.
template <int M, bool AFP32>
__global__ LB(256, 4) void mfma_gemm_kernel(const float* __restrict__ Af,
                                            const ushort* __restrict__ Ahi,
                                            const ushort* __restrict__ Alo,
                                            const ushort* __restrict__ Bhi,
                                            const ushort* __restrict__ Blo,
                                            ushort* __restrict__ Yb, float* __restrict__ Z, int n) {
  constexpr int DO = M / 2;
  constexpr int NWC = (M >= 256) ? 4 : 2;  // waves along cols
  constexpr int NWR = 4 / NWC;             // waves along rows
  constexpr int BROWS = 32 * NWR;
  const int tid = threadIdx.x;
  const int w = tid >> 6, l = tid & 63;
  const int q = l >> 4, m16 = l & 15;
  const int rowBase = blockIdx.x * BROWS + (w / NWC) * 32;
  const int colBase = (w % NWC) * 64;

  f32x4 acc[2][4] = {};
  int rrow[2];
#pragma unroll
  for (int i = 0; i < 2; ++i) {
    int r = rowBase + i * 16 + m16;
    rrow[i] = r < n ? r : n - 1;
  }

#pragma unroll
  for (int s = 0; s < 4; ++s) {
    const int ka = s * 32 + q * 8;
    short8 ah[2], al[2], bh[4], bo[4];
#pragma unroll
    for (int i = 0; i < 2; ++i) {
      size_t off = (size_t)rrow[i] * 128 + ka;
      if (AFP32) {
        split8(Af + off, ah[i], al[i]);
      } else {
        ah[i] = *(const short8*)(Ahi + off);
        al[i] = *(const short8*)(Alo + off);
      }
    }
    const int kb = s * 4 + q;
#pragma unroll
    for (int j = 0; j < 4; ++j) {
      size_t off = ((size_t)kb * M + colBase + j * 16 + m16) * 8;
      bh[j] = *(const short8*)(Bhi + off);
      bo[j] = *(const short8*)(Blo + off);
    }
#pragma unroll
    for (int i = 0; i < 2; ++i)
#pragma unroll
      for (int j = 0; j < 4; ++j) {
        acc[i][j] = __builtin_amdgcn_mfma_f32_16x16x32_bf16(ah[i], bh[j], acc[i][j], 0, 0, 0);
        acc[i][j] = __builtin_amdgcn_mfma_f32_16x16x32_bf16(ah[i], bo[j], acc[i][j], 0, 0, 0);
        acc[i][j] = __builtin_amdgcn_mfma_f32_16x16x32_bf16(al[i], bh[j], acc[i][j], 0, 0, 0);
      }
  }

#pragma unroll
  for (int i = 0; i < 2; ++i) {
    int rb = rowBase + i * 16 + q * 4;
#pragma unroll
    for (int j = 0; j < 4; ++j) {
      int c = colBase + j * 16 + m16;
#pragma unroll
      for (int r = 0; r < 4; ++r) {
        int row = rb + r;
        if (row < n) {
          float v = acc[i][j][r];
          if (c < DO)
            Yb[(size_t)row * DO + c] = bf16_rne(v);
          else
            Z[(size_t)row * DO + (c - DO)] = v;
        }
      }
    }
  }
}

// ---------------- aggregation ----------------
// One wave per node; (row_start, deg) arrays; indices block-loaded + shfl.
// All __shfl under wave-uniform control flow; only USES are predicated.
__global__ LB(256) void agg128_kernel(const ushort* __restrict__ Y, const float* __restrict__ Z,
                                      const int* __restrict__ row_start,
                                      const int* __restrict__ deg_arr, const int* __restrict__ srcs,
                                      const float* __restrict__ scale,
                                      const float* __restrict__ bsum, unsigned* __restrict__ Hhi,
                                      unsigned* __restrict__ Hlo, int n) {
  int node = blockIdx.x * 4 + (threadIdx.x >> 6);
  if (node >= n) return;  // wave-uniform exit
  const int lane = threadIdx.x & 63;
  const int li = lane & 31;
  const int half = lane >> 5;
  const int e0 = row_start[node];
  const int cnt = deg_arr[node];
  const int end = e0 + cnt;
  const int c1 = cnt < 64 ? cnt : 64;
  int idx = (lane < c1) ? srcs[e0 + lane] : 0;
  const uint2* Yu = (const uint2*)Y;  // row = 32 uint2
  float a0 = 0.f, a1 = 0.f, a2 = 0.f, a3 = 0.f;

  int j = 0;
  for (; j + 16 <= c1; j += 16) {  // 8 loads in flight
    int s[8];
#pragma unroll
    for (int t = 0; t < 8; ++t) s[t] = __shfl(idx, j + 2 * t + half);
    uint2 u[8];
#pragma unroll
    for (int t = 0; t < 8; ++t) u[t] = Yu[(size_t)s[t] * 32 + li];
#pragma unroll
    for (int t = 0; t < 8; ++t) {
      a0 += bits_to_f(u[t].x << 16);
      a1 += bits_to_f(u[t].x & 0xffff0000u);
      a2 += bits_to_f(u[t].y << 16);
      a3 += bits_to_f(u[t].y & 0xffff0000u);
    }
  }
  if (j + 8 <= c1) {
    int s[4];
#pragma unroll
    for (int t = 0; t < 4; ++t) s[t] = __shfl(idx, j + 2 * t + half);
    uint2 u[4];
#pragma unroll
    for (int t = 0; t < 4; ++t) u[t] = Yu[(size_t)s[t] * 32 + li];
#pragma unroll
    for (int t = 0; t < 4; ++t) {
      a0 += bits_to_f(u[t].x << 16);
      a1 += bits_to_f(u[t].x & 0xffff0000u);
      a2 += bits_to_f(u[t].y << 16);
      a3 += bits_to_f(u[t].y & 0xffff0000u);
    }
    j += 8;
  }
  for (; j + 2 <= c1; j += 2) {
    int s = __shfl(idx, j + half);
    uint2 u = Yu[(size_t)s * 32 + li];
    a0 += bits_to_f(u.x << 16);
    a1 += bits_to_f(u.x & 0xffff0000u);
    a2 += bits_to_f(u.y << 16);
    a3 += bits_to_f(u.y & 0xffff0000u);
  }
  if (j < c1) {  // uniform — shfl by ALL lanes, use by half 0 only
    int s = __shfl(idx, j);
    if (half == 0) {
      uint2 u = Yu[(size_t)s * 32 + li];
      a0 += bits_to_f(u.x << 16);
      a1 += bits_to_f(u.x & 0xffff0000u);
      a2 += bits_to_f(u.y << 16);
      a3 += bits_to_f(u.y & 0xffff0000u);
    }
  }
  if (cnt > 64) {
    int e = e0 + 64;
    for (; e + 2 <= end; e += 2) {
      int s = srcs[e + half];
      uint2 u = Yu[(size_t)s * 32 + li];
      a0 += bits_to_f(u.x << 16);
      a1 += bits_to_f(u.x & 0xffff0000u);
      a2 += bits_to_f(u.y << 16);
      a3 += bits_to_f(u.y & 0xffff0000u);
    }
    if (e < end && half == 0) {
      int s = srcs[e];
      uint2 u = Yu[(size_t)s * 32 + li];
      a0 += bits_to_f(u.x << 16);
      a1 += bits_to_f(u.x & 0xffff0000u);
      a2 += bits_to_f(u.y << 16);
      a3 += bits_to_f(u.y & 0xffff0000u);
    }
  }
  a0 += __shfl(a0, lane ^ 32);
  a1 += __shfl(a1, lane ^ 32);
  a2 += __shfl(a2, lane ^ 32);
  a3 += __shfl(a3, lane ^ 32);

  float sc = scale[node];
  float4 z = ((const float4*)Z)[(size_t)node * 32 + li];
  float4 b = ((const float4*)bsum)[li];
  float o0 = fmaxf(z.x + sc * a0 + b.x, 0.f);
  float o1 = fmaxf(z.y + sc * a1 + b.y, 0.f);
  float o2 = fmaxf(z.z + sc * a2 + b.z, 0.f);
  float o3 = fmaxf(z.w + sc * a3 + b.w, 0.f);
  unsigned short h0 = bf16_rne(o0), h1 = bf16_rne(o1), h2 = bf16_rne(o2), h3 = bf16_rne(o3);
  if (half == 0) {
    uint2 hp;
    hp.x = (unsigned)h0 | ((unsigned)h1 << 16);
    hp.y = (unsigned)h2 | ((unsigned)h3 << 16);
    ((uint2*)Hhi)[(size_t)node * 32 + li] = hp;
  } else {
    unsigned short l0 = bf16_rne(o0 - bf16_to_f(h0));
    unsigned short l1 = bf16_rne(o1 - bf16_to_f(h1));
    unsigned short l2 = bf16_rne(o2 - bf16_to_f(h2));
    unsigned short l3 = bf16_rne(o3 - bf16_to_f(h3));
    uint2 lp;
    lp.x = (unsigned)l0 | ((unsigned)l1 << 16);
    lp.y = (unsigned)l2 | ((unsigned)l3 << 16);
    ((uint2*)Hlo)[(size_t)node * 32 + li] = lp;
  }
}

// DO=64 final: quarter-wave (16 lanes x uint2 = 128B) per edge row.
__global__ LB(256) void agg64_kernel(const ushort* __restrict__ Y, const float* __restrict__ Z,
                                     const int* __restrict__ row_start,
                                     const int* __restrict__ deg_arr, const int* __restrict__ srcs,
                                     const float* __restrict__ scale, const float* __restrict__ bsum,
                                     float* __restrict__ out, int n) {
  int node = blockIdx.x * 4 + (threadIdx.x >> 6);
  if (node >= n) return;  // wave-uniform exit
  const int lane = threadIdx.x & 63;
  const int li = lane & 15;
  const int qt = lane >> 4;
  const int e0 = row_start[node];
  const int cnt = deg_arr[node];
  const int end = e0 + cnt;
  const int c1 = cnt < 64 ? cnt : 64;
  int idx = (lane < c1) ? srcs[e0 + lane] : 0;
  const uint2* Yu = (const uint2*)Y;  // row = 16 uint2
  float a0 = 0.f, a1 = 0.f, a2 = 0.f, a3 = 0.f;

  int j = 0;
  for (; j + 16 <= c1; j += 16) {
    int s0 = __shfl(idx, j + qt);
    int s1 = __shfl(idx, j + 4 + qt);
    int s2 = __shfl(idx, j + 8 + qt);
    int s3 = __shfl(idx, j + 12 + qt);
    uint2 u0 = Yu[(size_t)s0 * 16 + li];
    uint2 u1 = Yu[(size_t)s1 * 16 + li];
    uint2 u2 = Yu[(size_t)s2 * 16 + li];
    uint2 u3 = Yu[(size_t)s3 * 16 + li];
    a0 += bits_to_f(u0.x << 16) + bits_to_f(u1.x << 16) + bits_to_f(u2.x << 16) +
          bits_to_f(u3.x << 16);
    a1 += bits_to_f(u0.x & 0xffff0000u) + bits_to_f(u1.x & 0xffff0000u) +
          bits_to_f(u2.x & 0xffff0000u) + bits_to_f(u3.x & 0xffff0000u);
    a2 += bits_to_f(u0.y << 16) + bits_to_f(u1.y << 16) + bits_to_f(u2.y << 16) +
          bits_to_f(u3.y << 16);
    a3 += bits_to_f(u0.y & 0xffff0000u) + bits_to_f(u1.y & 0xffff0000u) +
          bits_to_f(u2.y & 0xffff0000u) + bits_to_f(u3.y & 0xffff0000u);
  }
  for (; j + 4 <= c1; j += 4) {
    int s = __shfl(idx, j + qt);
    uint2 u = Yu[(size_t)s * 16 + li];
    a0 += bits_to_f(u.x << 16);
    a1 += bits_to_f(u.x & 0xffff0000u);
    a2 += bits_to_f(u.y << 16);
    a3 += bits_to_f(u.y & 0xffff0000u);
  }
  {
    int rem = c1 - j;
    if (rem > 0) {  // uniform — shfl by ALL lanes, use predicated
      int s = __shfl(idx, j + (qt < rem ? qt : 0));
      if (qt < rem) {
        uint2 u = Yu[(size_t)s * 16 + li];
        a0 += bits_to_f(u.x << 16);
        a1 += bits_to_f(u.x & 0xffff0000u);
        a2 += bits_to_f(u.y << 16);
        a3 += bits_to_f(u.y & 0xffff0000u);
      }
    }
  }
  if (cnt > 64) {
    int e = e0 + 64;
    for (; e + 4 <= end; e += 4) {
      int s = srcs[e + qt];
      uint2 u = Yu[(size_t)s * 16 + li];
      a0 += bits_to_f(u.x << 16);
      a1 += bits_to_f(u.x & 0xffff0000u);
      a2 += bits_to_f(u.y << 16);
      a3 += bits_to_f(u.y & 0xffff0000u);
    }
    int rem = end - e;
    if (qt < rem) {
      int s = srcs[e + qt];
      uint2 u = Yu[(size_t)s * 16 + li];
      a0 += bits_to_f(u.x << 16);
      a1 += bits_to_f(u.x & 0xffff0000u);
      a2 += bits_to_f(u.y << 16);
      a3 += bits_to_f(u.y & 0xffff0000u);
    }
  }
  a0 += __shfl(a0, lane ^ 16);
  a1 += __shfl(a1, lane ^ 16);
  a2 += __shfl(a2, lane ^ 16);
  a3 += __shfl(a3, lane ^ 16);
  a0 += __shfl(a0, lane ^ 32);
  a1 += __shfl(a1, lane ^ 32);
  a2 += __shfl(a2, lane ^ 32);
  a3 += __shfl(a3, lane ^ 32);

  if (qt == 0) {
    float sc = scale[node];
    float4 z = ((const float4*)Z)[(size_t)node * 16 + li];
    float4 b = ((const float4*)bsum)[li];
    float4 o;
    o.x = z.x + sc * a0 + b.x;
    o.y = z.y + sc * a1 + b.y;
    o.z = z.z + sc * a2 + b.z;
    o.w = z.w + sc * a3 + b.w;
    ((float4*)out)[(size_t)node * 16 + li] = o;
  }
}

// ---------------- launch ----------------
extern "C" void kernel_launch(void* const* d_in, const int* in_sizes, int n_in,
                              void* d_out, int out_size, void* d_ws, size_t ws_size,
                              hipStream_t stream) {
  const float* x = (const float*)d_in[0];
  const int* ei = (const int*)d_in[1];
  const int N = in_sizes[0] / 128;
  const int E = in_sizes[3];
  const int* src = ei;
  const int* dst = ei + E;
  const float* Wl[3] = {(const float*)d_in[4], (const float*)d_in[9], (const float*)d_in[14]};
  const float* bl[3] = {(const float*)d_in[5], (const float*)d_in[10], (const float*)d_in[15]};
  const float* Wr[3] = {(const float*)d_in[6], (const float*)d_in[11], (const float*)d_in[16]};
  const float* Ws[3] = {(const float*)d_in[7], (const float*)d_in[12], (const float*)d_in[17]};
  const float* bs[3] = {(const float*)d_in[8], (const float*)d_in[13], (const float*)d_in[18]};

  const int NB = (N + 255) >> 8;

  size_t off = 0;
  auto carve = [&](size_t bytes) -> char* {
    char* p = (char*)d_ws + off;
    off += (bytes + 255) & ~(size_t)255;
    return p;
  };
  int* row_start = (int*)carve((size_t)N * 4);
  int* deg_arr = (int*)carve((size_t)N * 4);
  int* bcnt = (int*)carve((size_t)NB * 4);
  int* gcounter = (int*)carve(256);
  float* scale = (float*)carve((size_t)N * 4);
  int* srcs = (int*)carve((size_t)E * 4);
  int2* pairs = (int2*)carve((size_t)NB * BCAP * 8);
  ushort* Hhi = (ushort*)carve((size_t)N * 128 * 2);
  ushort* Hlo = (ushort*)carve((size_t)N * 128 * 2);
  ushort* Yb = (ushort*)carve((size_t)N * 128 * 2);
  float* Zf = (float*)carve((size_t)N * 128 * 4);
  ushort* Bh[3];
  ushort* Bo[3];
  float* bsum[3];
  for (int i = 0; i < 3; ++i) {
    Bh[i] = (ushort*)carve(128 * 256 * 2);
    Bo[i] = (ushort*)carve(128 * 256 * 2);
    bsum[i] = (float*)carve(128 * 4);
  }
  (void)ws_size;
  (void)n_in;
  (void)out_size;

  // K1: weights pack + zero bcnt/gcounter (must precede p1)
  wpack_all<<<dim3(128, 3), 256, 0, stream>>>(Wl[0], Wr[0], Ws[0], bl[0], bs[0], Wl[1], Wr[1],
                                              Ws[1], bl[1], bs[1], Wl[2], Wr[2], Ws[2], bl[2],
                                              bs[2], Bh[0], Bo[0], bsum[0], Bh[1], Bo[1], bsum[1],
                                              Bh[2], Bo[2], bsum[2], bcnt, gcounter, NB);
  // K2: bucket partition
  p1_bucket<<<(E + P1_CHUNK - 1) / P1_CHUNK, 256, 0, stream>>>(src, dst, bcnt, pairs, E);
  // K3: hist + scan + region-claim + place (no inter-block waits)
  p234_kernel<<<NB, 256, 0, stream>>>(pairs, bcnt, gcounter, row_start, deg_arr, scale, srcs, N);

  int g32 = (N + 31) / 32;   // M=256 GEMM grid (block = 32 rows x 256 cols)
  int g64 = (N + 63) / 64;   // M=128 GEMM grid (block = 64 rows x 128 cols)
  int gAgg = (N + 3) / 4;

  // layer 0 (A = fp32 x, split in-reg)
  mfma_gemm_kernel<256, true><<<g32, 256, 0, stream>>>(x, nullptr, nullptr, Bh[0], Bo[0], Yb, Zf, N);
  agg128_kernel<<<gAgg, 256, 0, stream>>>(Yb, Zf, row_start, deg_arr, srcs, scale, bsum[0],
                                          (unsigned*)Hhi, (unsigned*)Hlo, N);
  // layer 1
  mfma_gemm_kernel<256, false><<<g32, 256, 0, stream>>>(nullptr, Hhi, Hlo, Bh[1], Bo[1], Yb, Zf, N);
  agg128_kernel<<<gAgg, 256, 0, stream>>>(Yb, Zf, row_start, deg_arr, srcs, scale, bsum[1],
                                          (unsigned*)Hhi, (unsigned*)Hlo, N);
  // layer 2
  mfma_gemm_kernel<128, false><<<g64, 256, 0, stream>>>(nullptr, Hhi, Hlo, Bh[2], Bo[2], Yb, Zf, N);
  agg64_kernel<<<gAgg, 256, 0, stream>>>(Yb, Zf, row_start, deg_arr, srcs, scale, bsum[2],
                                         (float*)d_out, N);
}